// Round 9
// baseline (286.857 us; speedup 1.0000x reference)
//
#include <hip/hip_runtime.h>
#include <hip/hip_bf16.h>

#define BATCH 128
#define TLEN  65536
#define EDIM  512
#define SMAX  512

typedef __attribute__((ext_vector_type(8))) short   bf16x8;
typedef __attribute__((ext_vector_type(4))) float   floatx4;
typedef __attribute__((ext_vector_type(8))) ushort  ushort8;

__device__ __forceinline__ ushort f2bf(float f) {
  __hip_bfloat16 h = __float2bfloat16(f);  // RNE
  return *reinterpret_cast<ushort*>(&h);
}

// pack two float4 (8 consecutive k-elems) into one bf16x8 MFMA fragment
__device__ __forceinline__ bf16x8 cvt_frag(float4 lo, float4 hi) {
  ushort8 u;
  u[0] = f2bf(lo.x); u[1] = f2bf(lo.y); u[2] = f2bf(lo.z); u[3] = f2bf(lo.w);
  u[4] = f2bf(hi.x); u[5] = f2bf(hi.y); u[6] = f2bf(hi.z); u[7] = f2bf(hi.w);
  return __builtin_bit_cast(bf16x8, u);
}

__device__ __forceinline__ void gl_lds16_f(const float* g, float* l) {
  __builtin_amdgcn_global_load_lds(
      (const __attribute__((address_space(1))) void*)g,
      (__attribute__((address_space(3))) void*)l, 16, 0, 0);
}

// ---------------------------------------------------------------------------
// mask popcount: part[b*8+c] = popcount of 8192-int chunk c of sample b.
// ---------------------------------------------------------------------------
__global__ __launch_bounds__(256) void mask_partial_kernel(
    const int* __restrict__ mask, int* __restrict__ part) {
  const int b = blockIdx.x, c = blockIdx.y, t = threadIdx.x;
  const int4* row = (const int4*)(mask + (size_t)b * TLEN + (size_t)c * 8192);
  int s = 0;
  #pragma unroll
  for (int i = 0; i < 8; ++i) {
    int4 v = row[t + i * 256];
    s += (v.x != 0) + (v.y != 0) + (v.z != 0) + (v.w != 0);
  }
  #pragma unroll
  for (int off = 32; off > 0; off >>= 1) s += __shfl_down(s, off);
  __shared__ int partial[4];
  if ((t & 63) == 0) partial[t >> 6] = s;
  __syncthreads();
  if (t == 0)
    part[b * 8 + c] = partial[0] + partial[1] + partial[2] + partial[3];
}

// ---------------------------------------------------------------------------
// Single fused GEMM. 128x128 tile, 4 waves (2x2 of 64x64), BK=32,
// 16x16x32 bf16 MFMA, inputs f32 (no pre-convert pass):
//   A (signal): global_load_lds DMA as f32, double-buffered 2x16 KB LDS,
//     XOR-swizzled chunk layout (row r of 8 16B-chunks; position p holds
//     k-chunk p^(r&7)); converted f32->bf16 per-fragment in registers.
//   B (weights): per-lane direct global f32 loads (W <=1MB/branch, L2-hot,
//     no barrier dependency -> compiler pipelines them across iters),
//     converted in registers.
// XCD swizzle (R7-validated): L = group*32 + et*8 + slot; all 4 et-blocks of
// one A-strip share L%8 -> same XCD -> strip is one HBM fetch + L2 hits.
// nv summed inline from part[]; (st==0,et==0) block writes the mask row.
// Default launch bounds (R7 lesson: capping VGPRs spills the accumulator).
// ---------------------------------------------------------------------------
template <int W>
__device__ __forceinline__ void gemm_body(
    const float* __restrict__ sigb, const float* __restrict__ Wp,
    const float* __restrict__ bp, float* __restrict__ outb,
    int nv, int s0, int e0, int t, float* Af) {
  constexpr int ITERS = W / 32;
  const int wave = t >> 6, lane = t & 63;
  const int lane16 = lane & 15, quad = lane >> 4;
  const int ws_ = (wave >> 1) * 64, we_ = (wave & 1) * 64;

  // ---- A staging map: 1024 16B-chunks/stage, 4 per thread ----
  const float* ag[4];
  #pragma unroll
  for (int i = 0; i < 4; ++i) {
    const int c = t + i * 256;
    const int row = c >> 3, kc = (c & 7) ^ (row & 7);
    ag[i] = sigb + (size_t)(s0 + row) * W + kc * 4;
  }
  float* al[4];  // wave-uniform dest bases (HW adds lane*16B)
  #pragma unroll
  for (int i = 0; i < 4; ++i) al[i] = Af + (i * 256 + wave * 64) * 4;

  // ---- B fragment pointers (direct global, row-major W) ----
  const float* bpr[4];
  #pragma unroll
  for (int j = 0; j < 4; ++j)
    bpr[j] = Wp + (size_t)(e0 + we_ + j * 16 + lane16) * W + quad * 8;

  floatx4 acc[4][4];
  #pragma unroll
  for (int i = 0; i < 4; ++i)
    #pragma unroll
    for (int j = 0; j < 4; ++j) acc[i][j] = (floatx4)(0.f);

  // prologue: stage 0 -> buffer 0
  #pragma unroll
  for (int i = 0; i < 4; ++i) gl_lds16_f(ag[i], al[i]);
  __syncthreads();

  // lane-constant swizzled A read positions (floats)
  const int pa0 = ((quad * 2) ^ (lane16 & 7)) * 4;
  const int pa1 = ((quad * 2 + 1) ^ (lane16 & 7)) * 4;

  #pragma unroll
  for (int k = 0; k < ITERS; ++k) {
    if (k + 1 < ITERS) {  // issue next A stage into the other buffer
      const int ko = (k + 1) * 32;
      const int p = ((k + 1) & 1) * 4096;
      #pragma unroll
      for (int i = 0; i < 4; ++i) gl_lds16_f(ag[i] + ko, al[i] + p);
    }
    // B loads: no barrier coupling; compiler pipelines these
    float4 bl0[4], bl1[4];
    #pragma unroll
    for (int j = 0; j < 4; ++j) {
      bl0[j] = *(const float4*)(bpr[j] + k * 32);
      bl1[j] = *(const float4*)(bpr[j] + k * 32 + 4);
    }
    const float* A = Af + (k & 1) * 4096;
    bf16x8 af[4], bfr[4];
    #pragma unroll
    for (int i = 0; i < 4; ++i) {
      const int ra = ws_ + i * 16 + lane16;
      float4 a0 = *(const float4*)(A + ra * 32 + pa0);
      float4 a1 = *(const float4*)(A + ra * 32 + pa1);
      af[i] = cvt_frag(a0, a1);
    }
    #pragma unroll
    for (int j = 0; j < 4; ++j) bfr[j] = cvt_frag(bl0[j], bl1[j]);
    #pragma unroll
    for (int i = 0; i < 4; ++i)
      #pragma unroll
      for (int j = 0; j < 4; ++j)
        acc[i][j] = __builtin_amdgcn_mfma_f32_16x16x32_bf16(af[i], bfr[j], acc[i][j], 0, 0, 0);
    __syncthreads();
  }

  // epilogue: bias + row masking (exact zeros for rows >= nv)
  float bval[4];
  #pragma unroll
  for (int j = 0; j < 4; ++j) bval[j] = bp[e0 + we_ + j * 16 + lane16];
  #pragma unroll
  for (int i = 0; i < 4; ++i) {
    #pragma unroll
    for (int rr = 0; rr < 4; ++rr) {
      const int s_row = s0 + ws_ + i * 16 + quad * 4 + rr;
      const bool valid = s_row < nv;
      float* op = outb + (size_t)s_row * EDIM + e0 + we_ + lane16;
      #pragma unroll
      for (int j = 0; j < 4; ++j)
        op[j * 16] = valid ? (acc[i][j][rr] + bval[j]) : 0.f;
    }
  }
}

__global__ __launch_bounds__(256) void gemm_kernel(
    const float* __restrict__ signal, const int* __restrict__ branch_idx,
    const int* __restrict__ part,
    const float* __restrict__ W0, const float* __restrict__ bias0,
    const float* __restrict__ W1, const float* __restrict__ bias1,
    const float* __restrict__ W2, const float* __restrict__ bias2,
    float* __restrict__ out, float* __restrict__ out_mask) {
  // XCD-aware decode: slot(3b) | et(2b) | group(6b)
  const int L = blockIdx.x;
  const int slot = L & 7;
  const int et = (L >> 3) & 3;
  const int p = (L >> 5) * 8 + slot;   // 0..511
  const int st = p & 3;
  const int b = p >> 2;
  const int t = threadIdx.x;
  const int s0 = st * 128, e0 = et * 128;
  const int bi = branch_idx[b];
  const int S_b = 512 >> bi;
  float* outb = out + (size_t)b * SMAX * EDIM;

  // inline n_valid from part[] (written by mask_partial_kernel)
  int len = 0;
  #pragma unroll
  for (int i = 0; i < 8; ++i) len += part[b * 8 + i];
  const int nv = len / (128 << bi);

  if (st == 0 && et == 0) {  // one block per sample writes the mask row
    out_mask[(size_t)b * SMAX + t]       = (t < nv)       ? 1.0f : 0.0f;
    out_mask[(size_t)b * SMAX + 256 + t] = (256 + t < nv) ? 1.0f : 0.0f;
  }

  if (s0 >= S_b) {  // pure pad tile: zero-fill (harness poisons d_out)
    const float4 z = make_float4(0.f, 0.f, 0.f, 0.f);
    #pragma unroll
    for (int i = 0; i < 16; ++i) {
      int idx = t + i * 256;
      int r = idx >> 5, c = idx & 31;
      *(float4*)(outb + (size_t)(s0 + r) * EDIM + e0 + c * 4) = z;
    }
    return;
  }

  __shared__ __align__(16) float Af[2 * 4096];  // 32 KB: A f32, dbuf
  const float* sigb = signal + (size_t)b * TLEN;
  switch (bi) {
    case 0:  gemm_body<128>(sigb, W0, bias0, outb, nv, s0, e0, t, Af); break;
    case 1:  gemm_body<256>(sigb, W1, bias1, outb, nv, s0, e0, t, Af); break;
    default: gemm_body<512>(sigb, W2, bias2, outb, nv, s0, e0, t, Af); break;
  }
}

extern "C" void kernel_launch(void* const* d_in, const int* in_sizes, int n_in,
                              void* d_out, int out_size, void* d_ws, size_t ws_size,
                              hipStream_t stream) {
  const float* signal = (const float*)d_in[0];
  const int*   mask   = (const int*)d_in[1];
  const int*   bidx   = (const int*)d_in[2];
  const float* W0 = (const float*)d_in[3];
  const float* b0 = (const float*)d_in[4];
  const float* W1 = (const float*)d_in[5];
  const float* b1 = (const float*)d_in[6];
  const float* W2 = (const float*)d_in[7];
  const float* b2 = (const float*)d_in[8];

  float* out_tokens = (float*)d_out;
  float* out_mask   = (float*)d_out + (size_t)BATCH * SMAX * EDIM;
  int*   part       = (int*)d_ws;              // 1024 ints

  mask_partial_kernel<<<dim3(BATCH, 8), dim3(256), 0, stream>>>(mask, part);
  gemm_kernel<<<dim3(2048), dim3(256), 0, stream>>>(
      signal, bidx, part, W0, b0, W1, b1, W2, b2, out_tokens, out_mask);
}